// Round 12
// baseline (502.630 us; speedup 1.0000x reference)
//
#include <hip/hip_runtime.h>
#include <math.h>

// ---------------------------------------------------------------------------
// ImplicitFlowDecoder — R12: phase-start A-fragment preload (all 7 layers'
// ks=0 weights loaded at kernel start), LDS-only barriers (no vmcnt drain),
// H2 ping-pong (no internal barrier), H0 K-pad 288->272.
// Base: R11 fused layers, 32x32x16 MFMA, in-place LDS, 4 blocks/CU.
// ---------------------------------------------------------------------------

typedef short bf16x8 __attribute__((ext_vector_type(8)));
typedef float f32x16 __attribute__((ext_vector_type(16)));

constexpr int W8 = 64, H8 = 48, W16g = 32, H16g = 24, WF = 512, HF = 384;
constexpr int HWs8 = W8 * H8;      // 3072
constexpr int HWs16 = W16g * H16g; // 768
constexpr int MP = 64;
constexpr int NTH = 256;
constexpr int BPR = WF / MP;                // 8
constexpr int NBLK = 2 * HF * BPR;          // 6144

constexpr int S = 296;      // row stride (ushorts)
constexpr int SD = S / 2;   // 148 dwords

// d_ws layout (ushort elems)
constexpr int OFF_L1 = 0;        // K=192 N=256
constexpr int OFF_W2 = 49152;    // K=256 N=128
constexpr int OFF_L3 = 81920;    // K=256 N=256
constexpr int OFF_W4 = 147456;   // K=256 N=128
constexpr int OFF_H0 = 180224;   // K=272 (260 padded) N=256
constexpr int OFF_H1 = 249856;   // K=256 N=128
constexpr int OFF_H2 = 282624;   // K=128 N=64
constexpr int SWZ_TOTAL = 290816;
constexpr int OFF_BF = SWZ_TOTAL;          // fp32 fused biases: b1'[256], b3'[256]
constexpr int OFF_T = SWZ_TOTAL + 1024;    // transposed feat1 (bf16 [B][HW][C])
constexpr int NT_ELEMS = 2 * HWs8 * 128;   // 786432

// LDS-only barrier: our cross-thread data all flows through LDS, so lgkmcnt
// ordering + s_barrier suffices; skipping vmcnt(0) keeps weight/feature
// global loads in flight across phases (removes the m97-class drain stall).
__device__ __forceinline__ void ldsbar() {
  asm volatile("s_waitcnt lgkmcnt(0)\n\ts_barrier" ::: "memory");
}

__device__ __forceinline__ unsigned short f2bf(float f) {  // RNE (prep only)
  union { float f; unsigned u; } v; v.f = f;
  unsigned r = (v.u + 0x7fffu + ((v.u >> 16) & 1u)) >> 16;
  return (unsigned short)r;
}
__device__ __forceinline__ float bflo(unsigned u) {
  return __builtin_bit_cast(float, u << 16);
}
__device__ __forceinline__ float bfhi(unsigned u) {
  return __builtin_bit_cast(float, u & 0xffff0000u);
}
#if defined(__has_builtin)
#if __has_builtin(__builtin_amdgcn_cvt_pk_bf16_f32)
#define HAS_PK_BF16 1
#endif
#endif
__device__ __forceinline__ unsigned pack2bf(float a, float b) {
#ifdef HAS_PK_BF16
  typedef __bf16 bf2_t __attribute__((ext_vector_type(2)));
  bf2_t r = __builtin_amdgcn_cvt_pk_bf16_f32(a, b);
  return __builtin_bit_cast(unsigned, r);
#else
  unsigned ua = __builtin_bit_cast(unsigned, a) + 0x8000u;
  unsigned ub = __builtin_bit_cast(unsigned, b) + 0x8000u;
  return __builtin_amdgcn_perm(ub, ua, 0x07060302u);
#endif
}
// tanh-GELU in sigmoid form (~8 VALU; |err vs erf gelu| ~4e-4 abs)
__device__ __forceinline__ float gelu_fast(float x) {
  float t = fmaf(x * x, -0.07135557f, -1.59576912f);
  float e = __expf(x * t);
  return x * __builtin_amdgcn_rcpf(1.0f + e);
}

// ------------------------------- prep kernels ------------------------------
struct PrepParams {
  const float *Wc, *g1, *W1, *W2, *Wp, *g2, *W3, *W4, *h0, *h1, *h2;
  unsigned short* ws;
};

__global__ void prep_kernel(PrepParams pp) {
  const int K_[7]   = {192, 256, 256, 256, 260, 256, 128};
  const int Kp_[7]  = {192, 256, 256, 256, 272, 256, 128};
  const int OFF_[7] = {OFF_L1, OFF_W2, OFF_L3, OFF_W4, OFF_H0, OFF_H1, OFF_H2};
  for (int e = blockIdx.x * blockDim.x + threadIdx.x; e < SWZ_TOTAL;
       e += gridDim.x * blockDim.x) {
    int L = 0;
#pragma unroll
    for (int i = 1; i < 7; ++i) if (e >= OFF_[i]) L = i;
    int q = e - OFF_[L];
    int j = q & 7;
    int l = (q >> 3) & 63;
    int r = q >> 9;
    int nks = Kp_[L] >> 4;
    int ks = r % nks;
    int mt = r / nks;
    int n = mt * 32 + (l & 31);
    int k = ks * 16 + ((l >> 5) << 3) + j;
    float v = 0.0f;
    if (k < K_[L]) {
      if (L == 0) {
        if (k < 64) {  // (Wc @ diag(sig g1) @ W1)[k][n]
          float s = 0.0f;
          for (int q2 = 0; q2 < 128; ++q2) {
            float sg = 1.0f / (1.0f + expf(-pp.g1[q2]));
            s += pp.Wc[k * 128 + q2] * sg * pp.W1[q2 * 256 + n];
          }
          v = s;
        } else v = pp.W1[(k - 64) * 256 + n];
      } else if (L == 1) {
        v = pp.W2[k * 128 + n];
      } else if (L == 2) {
        if (k < 128) {  // (Wp @ diag(sig g2) @ W3)[k][n]
          float s = 0.0f;
          for (int q2 = 0; q2 < 128; ++q2) {
            float sg = 1.0f / (1.0f + expf(-pp.g2[q2]));
            s += pp.Wp[k * 128 + q2] * sg * pp.W3[q2 * 256 + n];
          }
          v = s;
        } else v = pp.W3[(k - 128) * 256 + n];
      } else if (L == 3) {
        v = pp.W4[k * 128 + n];
      } else if (L == 4) {
        v = pp.h0[k * 256 + n];
      } else if (L == 5) {
        v = pp.h1[k * 128 + n];
      } else {
        v = pp.h2[k * 64 + n];
      }
    }
    pp.ws[e] = f2bf(v);
  }
}

// fused biases: outB[0:256)=b1+bc@W1g, [256:512)=b3+bp@W3g  (fp32 in ws)
__global__ void prep_bias_kernel(const float* b1, const float* bc, const float* g1,
                                 const float* W1, const float* b3, const float* bp,
                                 const float* g2, const float* W3, float* outB) {
  int n = blockIdx.x * blockDim.x + threadIdx.x;
  if (n < 256) {
    float s = b1[n];
    for (int q = 0; q < 128; ++q) {
      float sg = 1.0f / (1.0f + expf(-g1[q]));
      s += bc[q] * sg * W1[q * 256 + n];
    }
    outB[n] = s;
  } else if (n < 512) {
    int m = n - 256;
    float s = b3[m];
    for (int q = 0; q < 128; ++q) {
      float sg = 1.0f / (1.0f + expf(-g2[q]));
      s += bp[q] * sg * W3[q * 256 + m];
    }
    outB[n] = s;
  }
}

// feat1 [B][C][H][W] fp32 -> ws [B][HW][C] bf16
__global__ void prep2_kernel(const float* __restrict__ f1, unsigned short* wsT) {
  for (int e = blockIdx.x * blockDim.x + threadIdx.x; e < NT_ELEMS;
       e += gridDim.x * blockDim.x) {
    int hw = e % HWs8;
    int c = (e / HWs8) & 127;
    int b = e / (HWs8 * 128);
    wsT[(b * HWs8 + hw) * 128 + c] = f2bf(f1[e]);
  }
}

// ------------------------------ main kernel --------------------------------
struct Params {
  const float* feat_s8; const float* feat_s16;
  const float* ctx_s8;  const float* coarse;
  const float* b2; const float* b4;
  const float* h0b; const float* h1b; const float* h2b;
  const float* h3w; const float* h3b;
  const unsigned short* ws;
  const unsigned short* wsT;
  const float* fbias;       // fused biases (fp32 in ws)
  float* out;
};

__device__ __forceinline__ void bilin_setup(float g, int Sg, int& i0, int& i1, float& w) {
  float s = (g + 1.0f) * (0.5f * Sg) - 0.5f;
  float f = floorf(s);
  w = s - f;
  int a = (int)f;
  i0 = min(max(a, 0), Sg - 1);
  i1 = min(max(a + 1, 0), Sg - 1);
}

// Patch index remap into buf's dead columns (float view):
// MAP 0: dword cols [96:128)  (ushort [192:256))  cap 2048 floats
// MAP 1: dword cols [128:144) (ushort [256:288))  cap 1024 floats
template<int MAP>
__device__ __forceinline__ int pmap(int n) {
  if (MAP == 0) return ((n >> 5) * SD) + 96 + (n & 31);
  else          return ((n >> 4) * SD) + 128 + (n & 15);
}

// preload the ks=0 A-fragments of a layer into registers (issued at kernel
// start; phase starts then don't stall on L2 weight latency)
template<int MT, int NT, int K>
__device__ __forceinline__ void loadA0(const unsigned short* __restrict__ Wsw,
                                       bf16x8* dst) {
  const int t = threadIdx.x;
  const int l = t & 63;
  const int wv = t >> 6;
  constexpr int nks = K >> 4;
  const int mt0 = (NT == 2) ? wv * MT : (wv >> 1);
  const unsigned short* abase = Wsw + (size_t)mt0 * nks * 512 + l * 8;
#pragma unroll
  for (int m = 0; m < MT; ++m)
    dst[m] = *(const bf16x8*)(abase + (size_t)m * nks * 512);
}

// 32x32x16 MFMA layer, K compile-time (full unroll).
// EP: 0=plain, 1=gelu, 2=relu. SYNC: barrier between B-reads and stores.
template<int MT, int NT, int EP, bool SYNC, int K>
__device__ __forceinline__ void mfma_layer(
    const unsigned short* __restrict__ Wsw,
    const float* __restrict__ bias,
    const unsigned short* actIn,
    unsigned short* actOut,
    const bf16x8* preA)
{
  const int t = threadIdx.x;
  const int l = t & 63;
  const int wv = t >> 6;
  constexpr int nks = K >> 4;
  const int mt0 = (NT == 2) ? wv * MT : (wv >> 1);
  const int ntb = (NT == 2) ? 0 : (wv & 1);
  const int lh = l >> 5;
  const int ll = l & 31;

  f32x16 acc[MT][NT];
#pragma unroll
  for (int m = 0; m < MT; ++m) {
#pragma unroll
    for (int g = 0; g < 4; ++g) {
      const int f0 = (mt0 + m) * 32 + g * 8 + (lh << 2);
      const float4 bv = *(const float4*)(bias + f0);
#pragma unroll
      for (int nt = 0; nt < NT; ++nt) {
        acc[m][nt][g * 4 + 0] = bv.x; acc[m][nt][g * 4 + 1] = bv.y;
        acc[m][nt][g * 4 + 2] = bv.z; acc[m][nt][g * 4 + 3] = bv.w;
      }
    }
  }

  const unsigned short* bbase = actIn + (ntb * 32 + ll) * S + (lh << 3);
  const unsigned short* abase = Wsw + (size_t)mt0 * nks * 512 + l * 8;

#pragma unroll
  for (int ks = 0; ks < nks; ++ks) {
    bf16x8 B[NT];
#pragma unroll
    for (int nt = 0; nt < NT; ++nt)
      B[nt] = *(const bf16x8*)(bbase + nt * 32 * S + ks * 16);
#pragma unroll
    for (int m = 0; m < MT; ++m) {
      bf16x8 A = (ks == 0) ? preA[m]
                           : *(const bf16x8*)(abase + ((size_t)m * nks + ks) * 512);
#pragma unroll
      for (int nt = 0; nt < NT; ++nt)
        acc[m][nt] = __builtin_amdgcn_mfma_f32_32x32x16_bf16(A, B[nt], acc[m][nt], 0, 0, 0);
    }
  }

  if (SYNC) ldsbar();

#pragma unroll
  for (int m = 0; m < MT; ++m) {
#pragma unroll
    for (int g = 0; g < 4; ++g) {
      const int f0 = (mt0 + m) * 32 + g * 8 + (lh << 2);
#pragma unroll
      for (int nt = 0; nt < NT; ++nt) {
        const int pt = (ntb + nt) * 32 + ll;
        float v[4];
        v[0] = acc[m][nt][g * 4 + 0]; v[1] = acc[m][nt][g * 4 + 1];
        v[2] = acc[m][nt][g * 4 + 2]; v[3] = acc[m][nt][g * 4 + 3];
        if (EP == 1) {
#pragma unroll
          for (int r = 0; r < 4; ++r) v[r] = gelu_fast(v[r]);
        } else if (EP == 2) {
#pragma unroll
          for (int r = 0; r < 4; ++r) v[r] = fmaxf(v[r], 0.0f);
        }
        uint2 pk;
        pk.x = pack2bf(v[0], v[1]);
        pk.y = pack2bf(v[2], v[3]);
        *(uint2*)(actOut + pt * S + f0) = pk;
      }
    }
  }
}

// stage a y-lerped patch into a remapped region of buf
template<int NCOL, int NCH, int MAP>
__device__ void stage_patch(const float* __restrict__ fm, int HW, int Wimg,
                            int base, int y0, int y1, float wy, float* bufF)
{
  const int items = NCOL * NCH;
  for (int e = threadIdx.x; e < items; e += NTH) {
    int ch = e / NCOL, col = e - ch * NCOL;
    int ca = min(base + col, Wimg - 1);
    const float* pp = fm + ch * HW;
    float v0 = pp[y0 * Wimg + ca];
    float v1 = pp[y1 * Wimg + ca];
    bufF[pmap<MAP>(col * (NCH + 2) + ch)] = fmaf(wy, v1 - v0, v0);
  }
}

// x-lerp from remapped patch into bf16 B-layout columns of buf
template<int PAIRS, int MAP, int CST>
__device__ void xlerp_tile(const float* __restrict__ bufF, const int* pcB, int shift,
                           const float* wxA, unsigned short* outBuf, int colOff)
{
  const int items = MP * PAIRS;
  for (int it = threadIdx.x; it < items; it += NTH) {
    int pr = it & (PAIRS - 1);
    int pt = it / PAIRS;
    int pc = pcB[pt] >> shift;
    int c0 = pc & 15, c1 = (pc >> 4) & 15;
    float wx = wxA[pt];
    float2 a = *(const float2*)(bufF + pmap<MAP>(c0 * CST + pr * 2));
    float2 b = *(const float2*)(bufF + pmap<MAP>(c1 * CST + pr * 2));
    float r0 = fmaf(wx, b.x - a.x, a.x);
    float r1 = fmaf(wx, b.y - a.y, a.y);
    *(unsigned*)(outBuf + pt * S + colOff + pr * 2) = pack2bf(r0, r1);
  }
}

// coalesced warped gather from transposed bf16 feat1 ([HW][C]); 4 ch/iter
__device__ void gather_tile_T(const unsigned short* __restrict__ T,
    const int* offT0, const int* offT1, const float* wxA, const float* wyA,
    unsigned short* outBuf, int colOff)
{
  for (int it = threadIdx.x; it < MP * 32; it += NTH) {
    int pt = it >> 5;
    int c4 = (it & 31) * 4;
    int e0 = offT0[pt], e1 = offT1[pt];
    int du = (e0 & 1) << 7;            // 0 or 128 (channel stride per +1 x)
    int o00 = e0 & ~1, o10 = e1 & ~1;
    float wx = wxA[pt], wy = wyA[pt];
    uint2 a00 = *(const uint2*)(T + o00 + c4);
    uint2 a01 = *(const uint2*)(T + o00 + du + c4);
    uint2 a10 = *(const uint2*)(T + o10 + c4);
    uint2 a11 = *(const uint2*)(T + o10 + du + c4);
    float w11 = wx * wy;
    float w01 = wx - w11, w10 = wy - w11, w00 = 1.0f - wx - wy + w11;
    float r0 = w00 * bflo(a00.x) + w01 * bflo(a01.x) + w10 * bflo(a10.x) + w11 * bflo(a11.x);
    float r1 = w00 * bfhi(a00.x) + w01 * bfhi(a01.x) + w10 * bfhi(a10.x) + w11 * bfhi(a11.x);
    float r2 = w00 * bflo(a00.y) + w01 * bflo(a01.y) + w10 * bflo(a10.y) + w11 * bflo(a11.y);
    float r3 = w00 * bfhi(a00.y) + w01 * bfhi(a01.y) + w10 * bfhi(a10.y) + w11 * bfhi(a11.y);
    uint2 pk;
    pk.x = pack2bf(r0, r1);
    pk.y = pack2bf(r2, r3);
    *(uint2*)(outBuf + pt * S + colOff + c4) = pk;
  }
}

__global__ __launch_bounds__(256, 4)
void ifd_kernel(Params p)
{
  __shared__ __align__(16) unsigned short buf[MP * S];   // 37888 B
  __shared__ int offT0[MP], offT1[MP];
  __shared__ int pcBoth[MP];
  __shared__ float w8x[MP], w16x[MP], wWx[MP], wWy[MP];
  __shared__ float caxA[MP], cayA[MP];
  __shared__ int uy8_0, uy8_1, uy16_0, uy16_1, ubase8, ubase16;
  __shared__ float uwy8, uwy16;

  float* bufF = (float*)buf;

  // --- phase-start A prefetch (issued before any barrier) ---
  bf16x8 preL1[2], preW2[1], preL3[2], preW4[1], preH0[2], preH1[1], preH2[1];
  loadA0<2, 2, 192>(p.ws + OFF_L1, preL1);
  loadA0<1, 2, 256>(p.ws + OFF_W2, preW2);
  loadA0<2, 2, 256>(p.ws + OFF_L3, preL3);
  loadA0<1, 2, 256>(p.ws + OFF_W4, preW4);
  loadA0<2, 2, 272>(p.ws + OFF_H0, preH0);
  loadA0<1, 2, 256>(p.ws + OFF_H1, preH1);
  loadA0<1, 1, 128>(p.ws + OFF_H2, preH2);

  const int blk = blockIdx.x;
  const int bb = blk / (HF * BPR);
  const int r = blk % (HF * BPR);
  const int y = r >> 3;
  const int xb = (r & (BPR - 1)) * MP;
  const int t = threadIdx.x;
  const float lim = 1.0f - 1e-6f;

  if (t < MP) {
    const int i = t;
    const int x = xb + i;
    float gx = (x + 0.5f) * (2.0f / WF) - 1.0f;
    float gy = (y + 0.5f) * (2.0f / HF) - 1.0f;
    gx = fminf(fmaxf(gx, -lim), lim);
    gy = fminf(fmaxf(gy, -lim), lim);

    float gx0 = fminf(fmaxf((xb + 0.5f) * (2.0f / WF) - 1.0f, -lim), lim);
    int base8 = min(max((int)floorf((gx0 + 1.0f) * 32.0f - 0.5f), 0), W8 - 1);
    int base16 = min(max((int)floorf((gx0 + 1.0f) * 16.0f - 0.5f), 0), W16g - 1);

    int x0, x1, y0, y1; float wx, wy;
    bilin_setup(gx, W8, x0, x1, wx);
    bilin_setup(gy, H8, y0, y1, wy);
    w8x[i] = wx;
    int o00 = y0 * W8 + x0, o01 = y0 * W8 + x1;
    int o10 = y1 * W8 + x0, o11 = y1 * W8 + x1;

    int a0, a1, b0i, b1i; float vx, vy;
    bilin_setup(gx, W16g, a0, a1, vx);
    bilin_setup(gy, H16g, b0i, b1i, vy);
    w16x[i] = vx;
    pcBoth[i] = (x0 - base8) | ((x1 - base8) << 4)
              | ((a0 - base16) << 8) | ((a1 - base16) << 12);

    if (i == 0) {
      uy8_0 = y0; uy8_1 = y1; uwy8 = wy;
      uy16_0 = b0i; uy16_1 = b1i; uwy16 = vy;
      ubase8 = base8; ubase16 = base16;
    }

    const float* cf = p.coarse + bb * 2 * HWs8;
    float c00 = cf[o00], c01 = cf[o01], c10 = cf[o10], c11 = cf[o11];
    float cx0 = fmaf(wx, c01 - c00, c00), cx1 = fmaf(wx, c11 - c10, c10);
    float cfx = fmaf(wy, cx1 - cx0, cx0);
    const float* cf2 = cf + HWs8;
    c00 = cf2[o00]; c01 = cf2[o01]; c10 = cf2[o10]; c11 = cf2[o11];
    cx0 = fmaf(wx, c01 - c00, c00); cx1 = fmaf(wx, c11 - c10, c10);
    float cfy = fmaf(wy, cx1 - cx0, cx0);
    float cax = cfx * 8.0f, cay = cfy * 8.0f;
    caxA[i] = cax; cayA[i] = cay;

    float wxn = gx + cax * (2.0f / WF);
    float wyn = gy + cay * (2.0f / HF);
    wxn = fminf(fmaxf(wxn, -lim), lim);
    wyn = fminf(fmaxf(wyn, -lim), lim);
    int u0, u1, v0, v1; float uw, vw;
    bilin_setup(wxn, W8, u0, u1, uw);
    bilin_setup(wyn, H8, v0, v1, vw);
    int du = u1 - u0;   // 0 or 1
    offT0[i] = ((v0 * W8 + u0) << 7) | du;
    offT1[i] = ((v1 * W8 + u0) << 7) | du;
    wWx[i] = uw; wWy[i] = vw;
  }
  ldsbar();

  // stage f8 -> MAP0 (ushort [192:256)); ctx -> MAP1 (ushort [256:288))
  stage_patch<10, 128, 0>(p.feat_s8 + bb * 128 * HWs8, HWs8, W8,
                          ubase8, uy8_0, uy8_1, uwy8, bufF);
  stage_patch<10, 64, 1>(p.ctx_s8 + bb * 64 * HWs8, HWs8, W8,
                         ubase8, uy8_0, uy8_1, uwy8, bufF);
  ldsbar();
  xlerp_tile<64, 0, 130>(bufF, pcBoth, 0, w8x, buf, 64);   // f8  -> [64:192)
  xlerp_tile<32, 1, 66>(bufF, pcBoth, 0, w8x, buf, 0);     // ctx -> [0:64)
  ldsbar();

  // stage f16 -> MAP1 (disjoint from L1 reads/writes); L1: [0:192) -> [0:256)
  stage_patch<6, 128, 1>(p.feat_s16 + bb * 128 * HWs16, HWs16, W16g,
                         ubase16, uy16_0, uy16_1, uwy16, bufF);
  mfma_layer<2, 2, 1, true, 192>(p.ws + OFF_L1, p.fbias, buf, buf, preL1);
  ldsbar();
  // W2: [0:256) K=256 -> [0:128); then f16 x-lerp -> [128:256)
  mfma_layer<1, 2, 0, true, 256>(p.ws + OFF_W2, p.b2, buf, buf, preW2);
  xlerp_tile<64, 1, 130>(bufF, pcBoth, 8, w16x, buf, 128);
  ldsbar();
  // L3 (WpW3g | W3): [0:256) -> [0:256) gelu
  mfma_layer<2, 2, 1, true, 256>(p.ws + OFF_L3, p.fbias + 256, buf, buf, preL3);
  ldsbar();
  // W4: [0:256) -> [0:128); gather -> [128:256); extras -> [256:272)
  mfma_layer<1, 2, 0, true, 256>(p.ws + OFF_W4, p.b4, buf, buf, preW4);
  gather_tile_T(p.wsT + bb * HWs8 * 128, offT0, offT1, wWx, wWy, buf, 128);
  for (int idx = t; idx < MP * 8; idx += NTH) {
    int row = idx >> 3, c = idx & 7;
    unsigned val = 0;
    if (c == 0) {
      float gx = fminf(fmaxf((xb + row + 0.5f) * (2.0f / WF) - 1.0f, -lim), lim);
      float gy = fminf(fmaxf((y + 0.5f) * (2.0f / HF) - 1.0f, -lim), lim);
      val = pack2bf(gx, gy);
    } else if (c == 1) {
      val = pack2bf(caxA[row] * (1.0f / WF), cayA[row] * (1.0f / HF));
    }
    *(unsigned*)(buf + row * S + 256 + c * 2) = val;
  }
  ldsbar();
  // flow head: H0 (K=272) and H1 in-place; H2 ping-pong [0:128)->[128:192)
  mfma_layer<2, 2, 2, true, 272>(p.ws + OFF_H0, p.h0b, buf, buf, preH0);
  ldsbar();
  mfma_layer<1, 2, 2, true, 256>(p.ws + OFF_H1, p.h1b, buf, buf, preH1);
  ldsbar();
  mfma_layer<1, 1, 2, false, 128>(p.ws + OFF_H2, p.h2b, buf, buf + 128, preH2);
  ldsbar();

  // final 64->2 + output (fp32); h3w from global (L2-hot)
  if (t < 128) {
    int i = t & 63, comp = t >> 6;
    float acc = p.h3b[comp];
    const unsigned short* rowp = buf + i * S + 128;
    const float* wp = p.h3w + comp;
#pragma unroll
    for (int k8 = 0; k8 < 8; ++k8) {
      uint4 av = *(const uint4*)(rowp + k8 * 8);
      const float* w8p = wp + k8 * 16;
      acc = fmaf(bflo(av.x), w8p[0], acc);
      acc = fmaf(bfhi(av.x), w8p[2], acc);
      acc = fmaf(bflo(av.y), w8p[4], acc);
      acc = fmaf(bfhi(av.y), w8p[6], acc);
      acc = fmaf(bflo(av.z), w8p[8], acc);
      acc = fmaf(bfhi(av.z), w8p[10], acc);
      acc = fmaf(bflo(av.w), w8p[12], acc);
      acc = fmaf(bfhi(av.w), w8p[14], acc);
    }
    float flow = (comp ? cayA[i] : caxA[i]) + acc * (comp ? (float)HF : (float)WF);
    p.out[((bb * 2 + comp) * HF + y) * WF + xb + i] = flow;
  }
}

extern "C" void kernel_launch(void* const* d_in, const int* in_sizes, int n_in,
                              void* d_out, int out_size, void* d_ws, size_t ws_size,
                              hipStream_t stream) {
  unsigned short* ws = (unsigned short*)d_ws;

  PrepParams pp;
  pp.Wc = (const float*)d_in[6];
  pp.g1 = (const float*)d_in[8];
  pp.W1 = (const float*)d_in[9];
  pp.W2 = (const float*)d_in[11];
  pp.Wp = (const float*)d_in[13];
  pp.g2 = (const float*)d_in[15];
  pp.W3 = (const float*)d_in[16];
  pp.W4 = (const float*)d_in[18];
  pp.h0 = (const float*)d_in[20];
  pp.h1 = (const float*)d_in[22];
  pp.h2 = (const float*)d_in[24];
  pp.ws = ws;
  hipLaunchKernelGGL(prep_kernel, dim3((SWZ_TOTAL + NTH - 1) / NTH), dim3(NTH), 0, stream, pp);
  hipLaunchKernelGGL(prep_bias_kernel, dim3(2), dim3(256), 0, stream,
                     (const float*)d_in[10], (const float*)d_in[7], (const float*)d_in[8],
                     (const float*)d_in[9],  (const float*)d_in[17], (const float*)d_in[14],
                     (const float*)d_in[15], (const float*)d_in[16], (float*)(ws + OFF_BF));
  hipLaunchKernelGGL(prep2_kernel, dim3(NT_ELEMS / NTH), dim3(NTH), 0, stream,
                     (const float*)d_in[2], ws + OFF_T);

  Params p;
  p.feat_s8  = (const float*)d_in[1];
  p.feat_s16 = (const float*)d_in[3];
  p.ctx_s8   = (const float*)d_in[4];
  p.coarse   = (const float*)d_in[5];
  p.b2  = (const float*)d_in[12];
  p.b4  = (const float*)d_in[19];
  p.h0b = (const float*)d_in[21];
  p.h1b = (const float*)d_in[23];
  p.h2b = (const float*)d_in[25];
  p.h3w = (const float*)d_in[26];
  p.h3b = (const float*)d_in[27];
  p.ws  = ws;
  p.wsT = ws + OFF_T;
  p.fbias = (const float*)(ws + OFF_BF);
  p.out = (float*)d_out;

  hipLaunchKernelGGL(ifd_kernel, dim3(NBLK), dim3(NTH), 0, stream, p);
}

// Round 13
// 470.810 us; speedup vs baseline: 1.0676x; 1.0676x over previous
//
#include <hip/hip_runtime.h>
#include <math.h>

// ---------------------------------------------------------------------------
// ImplicitFlowDecoder — R13: R11 + LDS-only barriers + H0 K-pad 272 + H2
// ping-pong. (R12's A-preload reverted: it spilled to scratch, +110 MB HBM.)
// Fused layers, 32x32x16 MFMA, in-place single-buffer LDS, 4 blocks/CU.
// ---------------------------------------------------------------------------

typedef short bf16x8 __attribute__((ext_vector_type(8)));
typedef float f32x16 __attribute__((ext_vector_type(16)));

constexpr int W8 = 64, H8 = 48, W16g = 32, H16g = 24, WF = 512, HF = 384;
constexpr int HWs8 = W8 * H8;      // 3072
constexpr int HWs16 = W16g * H16g; // 768
constexpr int MP = 64;
constexpr int NTH = 256;
constexpr int BPR = WF / MP;                // 8
constexpr int NBLK = 2 * HF * BPR;          // 6144

constexpr int S = 296;      // row stride (ushorts)
constexpr int SD = S / 2;   // 148 dwords

// d_ws layout (ushort elems)
constexpr int OFF_L1 = 0;        // K=192 N=256
constexpr int OFF_W2 = 49152;    // K=256 N=128
constexpr int OFF_L3 = 81920;    // K=256 N=256
constexpr int OFF_W4 = 147456;   // K=256 N=128
constexpr int OFF_H0 = 180224;   // K=272 (260 padded) N=256
constexpr int OFF_H1 = 249856;   // K=256 N=128
constexpr int OFF_H2 = 282624;   // K=128 N=64
constexpr int SWZ_TOTAL = 290816;
constexpr int OFF_BF = SWZ_TOTAL;          // fp32 fused biases: b1'[256], b3'[256]
constexpr int OFF_T = SWZ_TOTAL + 1024;    // transposed feat1 (bf16 [B][HW][C])
constexpr int NT_ELEMS = 2 * HWs8 * 128;   // 786432

// LDS-only barrier: all cross-thread data flows through LDS, so lgkmcnt +
// s_barrier suffices; skipping vmcnt(0) keeps global loads in flight.
__device__ __forceinline__ void ldsbar() {
  asm volatile("s_waitcnt lgkmcnt(0)\n\ts_barrier" ::: "memory");
}

__device__ __forceinline__ unsigned short f2bf(float f) {  // RNE (prep only)
  union { float f; unsigned u; } v; v.f = f;
  unsigned r = (v.u + 0x7fffu + ((v.u >> 16) & 1u)) >> 16;
  return (unsigned short)r;
}
__device__ __forceinline__ float bflo(unsigned u) {
  return __builtin_bit_cast(float, u << 16);
}
__device__ __forceinline__ float bfhi(unsigned u) {
  return __builtin_bit_cast(float, u & 0xffff0000u);
}
#if defined(__has_builtin)
#if __has_builtin(__builtin_amdgcn_cvt_pk_bf16_f32)
#define HAS_PK_BF16 1
#endif
#endif
__device__ __forceinline__ unsigned pack2bf(float a, float b) {
#ifdef HAS_PK_BF16
  typedef __bf16 bf2_t __attribute__((ext_vector_type(2)));
  bf2_t r = __builtin_amdgcn_cvt_pk_bf16_f32(a, b);
  return __builtin_bit_cast(unsigned, r);
#else
  unsigned ua = __builtin_bit_cast(unsigned, a) + 0x8000u;
  unsigned ub = __builtin_bit_cast(unsigned, b) + 0x8000u;
  return __builtin_amdgcn_perm(ub, ua, 0x07060302u);
#endif
}
// tanh-GELU in sigmoid form (~8 VALU; |err vs erf gelu| ~4e-4 abs)
__device__ __forceinline__ float gelu_fast(float x) {
  float t = fmaf(x * x, -0.07135557f, -1.59576912f);
  float e = __expf(x * t);
  return x * __builtin_amdgcn_rcpf(1.0f + e);
}

// ------------------------------- prep kernels ------------------------------
struct PrepParams {
  const float *Wc, *g1, *W1, *W2, *Wp, *g2, *W3, *W4, *h0, *h1, *h2;
  unsigned short* ws;
};

__global__ void prep_kernel(PrepParams pp) {
  const int K_[7]   = {192, 256, 256, 256, 260, 256, 128};
  const int Kp_[7]  = {192, 256, 256, 256, 272, 256, 128};
  const int OFF_[7] = {OFF_L1, OFF_W2, OFF_L3, OFF_W4, OFF_H0, OFF_H1, OFF_H2};
  for (int e = blockIdx.x * blockDim.x + threadIdx.x; e < SWZ_TOTAL;
       e += gridDim.x * blockDim.x) {
    int L = 0;
#pragma unroll
    for (int i = 1; i < 7; ++i) if (e >= OFF_[i]) L = i;
    int q = e - OFF_[L];
    int j = q & 7;
    int l = (q >> 3) & 63;
    int r = q >> 9;
    int nks = Kp_[L] >> 4;
    int ks = r % nks;
    int mt = r / nks;
    int n = mt * 32 + (l & 31);
    int k = ks * 16 + ((l >> 5) << 3) + j;
    float v = 0.0f;
    if (k < K_[L]) {
      if (L == 0) {
        if (k < 64) {  // (Wc @ diag(sig g1) @ W1)[k][n]
          float s = 0.0f;
          for (int q2 = 0; q2 < 128; ++q2) {
            float sg = 1.0f / (1.0f + expf(-pp.g1[q2]));
            s += pp.Wc[k * 128 + q2] * sg * pp.W1[q2 * 256 + n];
          }
          v = s;
        } else v = pp.W1[(k - 64) * 256 + n];
      } else if (L == 1) {
        v = pp.W2[k * 128 + n];
      } else if (L == 2) {
        if (k < 128) {  // (Wp @ diag(sig g2) @ W3)[k][n]
          float s = 0.0f;
          for (int q2 = 0; q2 < 128; ++q2) {
            float sg = 1.0f / (1.0f + expf(-pp.g2[q2]));
            s += pp.Wp[k * 128 + q2] * sg * pp.W3[q2 * 256 + n];
          }
          v = s;
        } else v = pp.W3[(k - 128) * 256 + n];
      } else if (L == 3) {
        v = pp.W4[k * 128 + n];
      } else if (L == 4) {
        v = pp.h0[k * 256 + n];
      } else if (L == 5) {
        v = pp.h1[k * 128 + n];
      } else {
        v = pp.h2[k * 64 + n];
      }
    }
    pp.ws[e] = f2bf(v);
  }
}

// fused biases: outB[0:256)=b1+bc@W1g, [256:512)=b3+bp@W3g  (fp32 in ws)
__global__ void prep_bias_kernel(const float* b1, const float* bc, const float* g1,
                                 const float* W1, const float* b3, const float* bp,
                                 const float* g2, const float* W3, float* outB) {
  int n = blockIdx.x * blockDim.x + threadIdx.x;
  if (n < 256) {
    float s = b1[n];
    for (int q = 0; q < 128; ++q) {
      float sg = 1.0f / (1.0f + expf(-g1[q]));
      s += bc[q] * sg * W1[q * 256 + n];
    }
    outB[n] = s;
  } else if (n < 512) {
    int m = n - 256;
    float s = b3[m];
    for (int q = 0; q < 128; ++q) {
      float sg = 1.0f / (1.0f + expf(-g2[q]));
      s += bp[q] * sg * W3[q * 256 + m];
    }
    outB[n] = s;
  }
}

// feat1 [B][C][H][W] fp32 -> ws [B][HW][C] bf16
__global__ void prep2_kernel(const float* __restrict__ f1, unsigned short* wsT) {
  for (int e = blockIdx.x * blockDim.x + threadIdx.x; e < NT_ELEMS;
       e += gridDim.x * blockDim.x) {
    int hw = e % HWs8;
    int c = (e / HWs8) & 127;
    int b = e / (HWs8 * 128);
    wsT[(b * HWs8 + hw) * 128 + c] = f2bf(f1[e]);
  }
}

// ------------------------------ main kernel --------------------------------
struct Params {
  const float* feat_s8; const float* feat_s16;
  const float* ctx_s8;  const float* coarse;
  const float* b2; const float* b4;
  const float* h0b; const float* h1b; const float* h2b;
  const float* h3w; const float* h3b;
  const unsigned short* ws;
  const unsigned short* wsT;
  const float* fbias;       // fused biases (fp32 in ws)
  float* out;
};

__device__ __forceinline__ void bilin_setup(float g, int Sg, int& i0, int& i1, float& w) {
  float s = (g + 1.0f) * (0.5f * Sg) - 0.5f;
  float f = floorf(s);
  w = s - f;
  int a = (int)f;
  i0 = min(max(a, 0), Sg - 1);
  i1 = min(max(a + 1, 0), Sg - 1);
}

// Patch index remap into buf's dead columns (float view):
// MAP 0: dword cols [96:128)  (ushort [192:256))  cap 2048 floats
// MAP 1: dword cols [128:144) (ushort [256:288))  cap 1024 floats
template<int MAP>
__device__ __forceinline__ int pmap(int n) {
  if (MAP == 0) return ((n >> 5) * SD) + 96 + (n & 31);
  else          return ((n >> 4) * SD) + 128 + (n & 15);
}

// 32x32x16 MFMA layer, K compile-time (full unroll).
// EP: 0=plain, 1=gelu, 2=relu. SYNC: barrier between B-reads and stores.
template<int MT, int NT, int EP, bool SYNC, int K>
__device__ __forceinline__ void mfma_layer(
    const unsigned short* __restrict__ Wsw,
    const float* __restrict__ bias,
    const unsigned short* actIn,
    unsigned short* actOut)
{
  const int t = threadIdx.x;
  const int l = t & 63;
  const int wv = t >> 6;
  constexpr int nks = K >> 4;
  const int mt0 = (NT == 2) ? wv * MT : (wv >> 1);
  const int ntb = (NT == 2) ? 0 : (wv & 1);
  const int lh = l >> 5;
  const int ll = l & 31;

  f32x16 acc[MT][NT];
#pragma unroll
  for (int m = 0; m < MT; ++m) {
#pragma unroll
    for (int g = 0; g < 4; ++g) {
      const int f0 = (mt0 + m) * 32 + g * 8 + (lh << 2);
      const float4 bv = *(const float4*)(bias + f0);
#pragma unroll
      for (int nt = 0; nt < NT; ++nt) {
        acc[m][nt][g * 4 + 0] = bv.x; acc[m][nt][g * 4 + 1] = bv.y;
        acc[m][nt][g * 4 + 2] = bv.z; acc[m][nt][g * 4 + 3] = bv.w;
      }
    }
  }

  const unsigned short* bbase = actIn + (ntb * 32 + ll) * S + (lh << 3);
  const unsigned short* abase = Wsw + (size_t)mt0 * nks * 512 + l * 8;

#pragma unroll
  for (int ks = 0; ks < nks; ++ks) {
    bf16x8 B[NT];
#pragma unroll
    for (int nt = 0; nt < NT; ++nt)
      B[nt] = *(const bf16x8*)(bbase + nt * 32 * S + ks * 16);
#pragma unroll
    for (int m = 0; m < MT; ++m) {
      bf16x8 A = *(const bf16x8*)(abase + ((size_t)m * nks + ks) * 512);
#pragma unroll
      for (int nt = 0; nt < NT; ++nt)
        acc[m][nt] = __builtin_amdgcn_mfma_f32_32x32x16_bf16(A, B[nt], acc[m][nt], 0, 0, 0);
    }
  }

  if (SYNC) ldsbar();

#pragma unroll
  for (int m = 0; m < MT; ++m) {
#pragma unroll
    for (int g = 0; g < 4; ++g) {
      const int f0 = (mt0 + m) * 32 + g * 8 + (lh << 2);
#pragma unroll
      for (int nt = 0; nt < NT; ++nt) {
        const int pt = (ntb + nt) * 32 + ll;
        float v[4];
        v[0] = acc[m][nt][g * 4 + 0]; v[1] = acc[m][nt][g * 4 + 1];
        v[2] = acc[m][nt][g * 4 + 2]; v[3] = acc[m][nt][g * 4 + 3];
        if (EP == 1) {
#pragma unroll
          for (int r = 0; r < 4; ++r) v[r] = gelu_fast(v[r]);
        } else if (EP == 2) {
#pragma unroll
          for (int r = 0; r < 4; ++r) v[r] = fmaxf(v[r], 0.0f);
        }
        uint2 pk;
        pk.x = pack2bf(v[0], v[1]);
        pk.y = pack2bf(v[2], v[3]);
        *(uint2*)(actOut + pt * S + f0) = pk;
      }
    }
  }
}

// stage a y-lerped patch into a remapped region of buf
template<int NCOL, int NCH, int MAP>
__device__ void stage_patch(const float* __restrict__ fm, int HW, int Wimg,
                            int base, int y0, int y1, float wy, float* bufF)
{
  const int items = NCOL * NCH;
  for (int e = threadIdx.x; e < items; e += NTH) {
    int ch = e / NCOL, col = e - ch * NCOL;
    int ca = min(base + col, Wimg - 1);
    const float* pp = fm + ch * HW;
    float v0 = pp[y0 * Wimg + ca];
    float v1 = pp[y1 * Wimg + ca];
    bufF[pmap<MAP>(col * (NCH + 2) + ch)] = fmaf(wy, v1 - v0, v0);
  }
}

// x-lerp from remapped patch into bf16 B-layout columns of buf
template<int PAIRS, int MAP, int CST>
__device__ void xlerp_tile(const float* __restrict__ bufF, const int* pcB, int shift,
                           const float* wxA, unsigned short* outBuf, int colOff)
{
  const int items = MP * PAIRS;
  for (int it = threadIdx.x; it < items; it += NTH) {
    int pr = it & (PAIRS - 1);
    int pt = it / PAIRS;
    int pc = pcB[pt] >> shift;
    int c0 = pc & 15, c1 = (pc >> 4) & 15;
    float wx = wxA[pt];
    float2 a = *(const float2*)(bufF + pmap<MAP>(c0 * CST + pr * 2));
    float2 b = *(const float2*)(bufF + pmap<MAP>(c1 * CST + pr * 2));
    float r0 = fmaf(wx, b.x - a.x, a.x);
    float r1 = fmaf(wx, b.y - a.y, a.y);
    *(unsigned*)(outBuf + pt * S + colOff + pr * 2) = pack2bf(r0, r1);
  }
}

// coalesced warped gather from transposed bf16 feat1 ([HW][C]); 4 ch/iter
__device__ void gather_tile_T(const unsigned short* __restrict__ T,
    const int* offT0, const int* offT1, const float* wxA, const float* wyA,
    unsigned short* outBuf, int colOff)
{
  for (int it = threadIdx.x; it < MP * 32; it += NTH) {
    int pt = it >> 5;
    int c4 = (it & 31) * 4;
    int e0 = offT0[pt], e1 = offT1[pt];
    int du = (e0 & 1) << 7;            // 0 or 128 (channel stride per +1 x)
    int o00 = e0 & ~1, o10 = e1 & ~1;
    float wx = wxA[pt], wy = wyA[pt];
    uint2 a00 = *(const uint2*)(T + o00 + c4);
    uint2 a01 = *(const uint2*)(T + o00 + du + c4);
    uint2 a10 = *(const uint2*)(T + o10 + c4);
    uint2 a11 = *(const uint2*)(T + o10 + du + c4);
    float w11 = wx * wy;
    float w01 = wx - w11, w10 = wy - w11, w00 = 1.0f - wx - wy + w11;
    float r0 = w00 * bflo(a00.x) + w01 * bflo(a01.x) + w10 * bflo(a10.x) + w11 * bflo(a11.x);
    float r1 = w00 * bfhi(a00.x) + w01 * bfhi(a01.x) + w10 * bfhi(a10.x) + w11 * bfhi(a11.x);
    float r2 = w00 * bflo(a00.y) + w01 * bflo(a01.y) + w10 * bflo(a10.y) + w11 * bflo(a11.y);
    float r3 = w00 * bfhi(a00.y) + w01 * bfhi(a01.y) + w10 * bfhi(a10.y) + w11 * bfhi(a11.y);
    uint2 pk;
    pk.x = pack2bf(r0, r1);
    pk.y = pack2bf(r2, r3);
    *(uint2*)(outBuf + pt * S + colOff + c4) = pk;
  }
}

__global__ __launch_bounds__(256, 4)
void ifd_kernel(Params p)
{
  __shared__ __align__(16) unsigned short buf[MP * S];   // 37888 B
  __shared__ int offT0[MP], offT1[MP];
  __shared__ int pcBoth[MP];
  __shared__ float w8x[MP], w16x[MP], wWx[MP], wWy[MP];
  __shared__ float caxA[MP], cayA[MP];
  __shared__ int uy8_0, uy8_1, uy16_0, uy16_1, ubase8, ubase16;
  __shared__ float uwy8, uwy16;

  float* bufF = (float*)buf;

  const int blk = blockIdx.x;
  const int bb = blk / (HF * BPR);
  const int r = blk % (HF * BPR);
  const int y = r >> 3;
  const int xb = (r & (BPR - 1)) * MP;
  const int t = threadIdx.x;
  const float lim = 1.0f - 1e-6f;

  if (t < MP) {
    const int i = t;
    const int x = xb + i;
    float gx = (x + 0.5f) * (2.0f / WF) - 1.0f;
    float gy = (y + 0.5f) * (2.0f / HF) - 1.0f;
    gx = fminf(fmaxf(gx, -lim), lim);
    gy = fminf(fmaxf(gy, -lim), lim);

    float gx0 = fminf(fmaxf((xb + 0.5f) * (2.0f / WF) - 1.0f, -lim), lim);
    int base8 = min(max((int)floorf((gx0 + 1.0f) * 32.0f - 0.5f), 0), W8 - 1);
    int base16 = min(max((int)floorf((gx0 + 1.0f) * 16.0f - 0.5f), 0), W16g - 1);

    int x0, x1, y0, y1; float wx, wy;
    bilin_setup(gx, W8, x0, x1, wx);
    bilin_setup(gy, H8, y0, y1, wy);
    w8x[i] = wx;
    int o00 = y0 * W8 + x0, o01 = y0 * W8 + x1;
    int o10 = y1 * W8 + x0, o11 = y1 * W8 + x1;

    int a0, a1, b0i, b1i; float vx, vy;
    bilin_setup(gx, W16g, a0, a1, vx);
    bilin_setup(gy, H16g, b0i, b1i, vy);
    w16x[i] = vx;
    pcBoth[i] = (x0 - base8) | ((x1 - base8) << 4)
              | ((a0 - base16) << 8) | ((a1 - base16) << 12);

    if (i == 0) {
      uy8_0 = y0; uy8_1 = y1; uwy8 = wy;
      uy16_0 = b0i; uy16_1 = b1i; uwy16 = vy;
      ubase8 = base8; ubase16 = base16;
    }

    const float* cf = p.coarse + bb * 2 * HWs8;
    float c00 = cf[o00], c01 = cf[o01], c10 = cf[o10], c11 = cf[o11];
    float cx0 = fmaf(wx, c01 - c00, c00), cx1 = fmaf(wx, c11 - c10, c10);
    float cfx = fmaf(wy, cx1 - cx0, cx0);
    const float* cf2 = cf + HWs8;
    c00 = cf2[o00]; c01 = cf2[o01]; c10 = cf2[o10]; c11 = cf2[o11];
    cx0 = fmaf(wx, c01 - c00, c00); cx1 = fmaf(wx, c11 - c10, c10);
    float cfy = fmaf(wy, cx1 - cx0, cx0);
    float cax = cfx * 8.0f, cay = cfy * 8.0f;
    caxA[i] = cax; cayA[i] = cay;

    float wxn = gx + cax * (2.0f / WF);
    float wyn = gy + cay * (2.0f / HF);
    wxn = fminf(fmaxf(wxn, -lim), lim);
    wyn = fminf(fmaxf(wyn, -lim), lim);
    int u0, u1, v0, v1; float uw, vw;
    bilin_setup(wxn, W8, u0, u1, uw);
    bilin_setup(wyn, H8, v0, v1, vw);
    int du = u1 - u0;   // 0 or 1
    offT0[i] = ((v0 * W8 + u0) << 7) | du;
    offT1[i] = ((v1 * W8 + u0) << 7) | du;
    wWx[i] = uw; wWy[i] = vw;
  }
  ldsbar();

  // stage f8 -> MAP0 (ushort [192:256)); ctx -> MAP1 (ushort [256:288))
  stage_patch<10, 128, 0>(p.feat_s8 + bb * 128 * HWs8, HWs8, W8,
                          ubase8, uy8_0, uy8_1, uwy8, bufF);
  stage_patch<10, 64, 1>(p.ctx_s8 + bb * 64 * HWs8, HWs8, W8,
                         ubase8, uy8_0, uy8_1, uwy8, bufF);
  ldsbar();
  xlerp_tile<64, 0, 130>(bufF, pcBoth, 0, w8x, buf, 64);   // f8  -> [64:192)
  xlerp_tile<32, 1, 66>(bufF, pcBoth, 0, w8x, buf, 0);     // ctx -> [0:64)
  ldsbar();

  // stage f16 -> MAP1 (disjoint from L1 reads/writes); L1: [0:192) -> [0:256)
  stage_patch<6, 128, 1>(p.feat_s16 + bb * 128 * HWs16, HWs16, W16g,
                         ubase16, uy16_0, uy16_1, uwy16, bufF);
  mfma_layer<2, 2, 1, true, 192>(p.ws + OFF_L1, p.fbias, buf, buf);
  ldsbar();
  // W2: [0:256) K=256 -> [0:128); then f16 x-lerp -> [128:256)
  mfma_layer<1, 2, 0, true, 256>(p.ws + OFF_W2, p.b2, buf, buf);
  xlerp_tile<64, 1, 130>(bufF, pcBoth, 8, w16x, buf, 128);
  ldsbar();
  // L3 (WpW3g | W3): [0:256) -> [0:256) gelu
  mfma_layer<2, 2, 1, true, 256>(p.ws + OFF_L3, p.fbias + 256, buf, buf);
  ldsbar();
  // W4: [0:256) -> [0:128); gather -> [128:256); extras -> [256:272)
  mfma_layer<1, 2, 0, true, 256>(p.ws + OFF_W4, p.b4, buf, buf);
  gather_tile_T(p.wsT + bb * HWs8 * 128, offT0, offT1, wWx, wWy, buf, 128);
  for (int idx = t; idx < MP * 8; idx += NTH) {
    int row = idx >> 3, c = idx & 7;
    unsigned val = 0;
    if (c == 0) {
      float gx = fminf(fmaxf((xb + row + 0.5f) * (2.0f / WF) - 1.0f, -lim), lim);
      float gy = fminf(fmaxf((y + 0.5f) * (2.0f / HF) - 1.0f, -lim), lim);
      val = pack2bf(gx, gy);
    } else if (c == 1) {
      val = pack2bf(caxA[row] * (1.0f / WF), cayA[row] * (1.0f / HF));
    }
    *(unsigned*)(buf + row * S + 256 + c * 2) = val;
  }
  ldsbar();
  // flow head: H0 (K=272) and H1 in-place; H2 ping-pong [0:128)->[128:192)
  mfma_layer<2, 2, 2, true, 272>(p.ws + OFF_H0, p.h0b, buf, buf);
  ldsbar();
  mfma_layer<1, 2, 2, true, 256>(p.ws + OFF_H1, p.h1b, buf, buf);
  ldsbar();
  mfma_layer<1, 1, 2, false, 128>(p.ws + OFF_H2, p.h2b, buf, buf + 128);
  ldsbar();

  // final 64->2 + output (fp32); h3w from global (L2-hot)
  if (t < 128) {
    int i = t & 63, comp = t >> 6;
    float acc = p.h3b[comp];
    const unsigned short* rowp = buf + i * S + 128;
    const float* wp = p.h3w + comp;
#pragma unroll
    for (int k8 = 0; k8 < 8; ++k8) {
      uint4 av = *(const uint4*)(rowp + k8 * 8);
      const float* w8p = wp + k8 * 16;
      acc = fmaf(bflo(av.x), w8p[0], acc);
      acc = fmaf(bfhi(av.x), w8p[2], acc);
      acc = fmaf(bflo(av.y), w8p[4], acc);
      acc = fmaf(bfhi(av.y), w8p[6], acc);
      acc = fmaf(bflo(av.z), w8p[8], acc);
      acc = fmaf(bfhi(av.z), w8p[10], acc);
      acc = fmaf(bflo(av.w), w8p[12], acc);
      acc = fmaf(bfhi(av.w), w8p[14], acc);
    }
    float flow = (comp ? cayA[i] : caxA[i]) + acc * (comp ? (float)HF : (float)WF);
    p.out[((bb * 2 + comp) * HF + y) * WF + xb + i] = flow;
  }
}

extern "C" void kernel_launch(void* const* d_in, const int* in_sizes, int n_in,
                              void* d_out, int out_size, void* d_ws, size_t ws_size,
                              hipStream_t stream) {
  unsigned short* ws = (unsigned short*)d_ws;

  PrepParams pp;
  pp.Wc = (const float*)d_in[6];
  pp.g1 = (const float*)d_in[8];
  pp.W1 = (const float*)d_in[9];
  pp.W2 = (const float*)d_in[11];
  pp.Wp = (const float*)d_in[13];
  pp.g2 = (const float*)d_in[15];
  pp.W3 = (const float*)d_in[16];
  pp.W4 = (const float*)d_in[18];
  pp.h0 = (const float*)d_in[20];
  pp.h1 = (const float*)d_in[22];
  pp.h2 = (const float*)d_in[24];
  pp.ws = ws;
  hipLaunchKernelGGL(prep_kernel, dim3((SWZ_TOTAL + NTH - 1) / NTH), dim3(NTH), 0, stream, pp);
  hipLaunchKernelGGL(prep_bias_kernel, dim3(2), dim3(256), 0, stream,
                     (const float*)d_in[10], (const float*)d_in[7], (const float*)d_in[8],
                     (const float*)d_in[9],  (const float*)d_in[17], (const float*)d_in[14],
                     (const float*)d_in[15], (const float*)d_in[16], (float*)(ws + OFF_BF));
  hipLaunchKernelGGL(prep2_kernel, dim3(NT_ELEMS / NTH), dim3(NTH), 0, stream,
                     (const float*)d_in[2], ws + OFF_T);

  Params p;
  p.feat_s8  = (const float*)d_in[1];
  p.feat_s16 = (const float*)d_in[3];
  p.ctx_s8   = (const float*)d_in[4];
  p.coarse   = (const float*)d_in[5];
  p.b2  = (const float*)d_in[12];
  p.b4  = (const float*)d_in[19];
  p.h0b = (const float*)d_in[21];
  p.h1b = (const float*)d_in[23];
  p.h2b = (const float*)d_in[25];
  p.h3w = (const float*)d_in[26];
  p.h3b = (const float*)d_in[27];
  p.ws  = ws;
  p.wsT = ws + OFF_T;
  p.fbias = (const float*)(ws + OFF_BF);
  p.out = (float*)d_out;

  hipLaunchKernelGGL(ifd_kernel, dim3(NBLK), dim3(NTH), 0, stream, p);
}

// Round 14
// 462.400 us; speedup vs baseline: 1.0870x; 1.0182x over previous
//
#include <hip/hip_runtime.h>
#include <math.h>

// ---------------------------------------------------------------------------
// ImplicitFlowDecoder — R14: early patch staging (row-uniform params computed
// by all threads; f8/ctx global loads issued before the setup barrier),
// exp2-folded GELU. Base: R13 (fused layers, 32x32x16 MFMA, LDS-only
// barriers, in-place single-buffer LDS, 4 blocks/CU).
// ---------------------------------------------------------------------------

typedef short bf16x8 __attribute__((ext_vector_type(8)));
typedef float f32x16 __attribute__((ext_vector_type(16)));

constexpr int W8 = 64, H8 = 48, W16g = 32, H16g = 24, WF = 512, HF = 384;
constexpr int HWs8 = W8 * H8;      // 3072
constexpr int HWs16 = W16g * H16g; // 768
constexpr int MP = 64;
constexpr int NTH = 256;
constexpr int BPR = WF / MP;                // 8
constexpr int NBLK = 2 * HF * BPR;          // 6144

constexpr int S = 296;      // row stride (ushorts)
constexpr int SD = S / 2;   // 148 dwords

// d_ws layout (ushort elems)
constexpr int OFF_L1 = 0;        // K=192 N=256
constexpr int OFF_W2 = 49152;    // K=256 N=128
constexpr int OFF_L3 = 81920;    // K=256 N=256
constexpr int OFF_W4 = 147456;   // K=256 N=128
constexpr int OFF_H0 = 180224;   // K=272 (260 padded) N=256
constexpr int OFF_H1 = 249856;   // K=256 N=128
constexpr int OFF_H2 = 282624;   // K=128 N=64
constexpr int SWZ_TOTAL = 290816;
constexpr int OFF_BF = SWZ_TOTAL;          // fp32 fused biases: b1'[256], b3'[256]
constexpr int OFF_T = SWZ_TOTAL + 1024;    // transposed feat1 (bf16 [B][HW][C])
constexpr int NT_ELEMS = 2 * HWs8 * 128;   // 786432

// LDS-only barrier: all cross-thread data flows through LDS, so lgkmcnt +
// s_barrier suffices; skipping vmcnt(0) keeps global loads in flight.
__device__ __forceinline__ void ldsbar() {
  asm volatile("s_waitcnt lgkmcnt(0)\n\ts_barrier" ::: "memory");
}

__device__ __forceinline__ unsigned short f2bf(float f) {  // RNE (prep only)
  union { float f; unsigned u; } v; v.f = f;
  unsigned r = (v.u + 0x7fffu + ((v.u >> 16) & 1u)) >> 16;
  return (unsigned short)r;
}
__device__ __forceinline__ float bflo(unsigned u) {
  return __builtin_bit_cast(float, u << 16);
}
__device__ __forceinline__ float bfhi(unsigned u) {
  return __builtin_bit_cast(float, u & 0xffff0000u);
}
#if defined(__has_builtin)
#if __has_builtin(__builtin_amdgcn_cvt_pk_bf16_f32)
#define HAS_PK_BF16 1
#endif
#endif
__device__ __forceinline__ unsigned pack2bf(float a, float b) {
#ifdef HAS_PK_BF16
  typedef __bf16 bf2_t __attribute__((ext_vector_type(2)));
  bf2_t r = __builtin_amdgcn_cvt_pk_bf16_f32(a, b);
  return __builtin_bit_cast(unsigned, r);
#else
  unsigned ua = __builtin_bit_cast(unsigned, a) + 0x8000u;
  unsigned ub = __builtin_bit_cast(unsigned, b) + 0x8000u;
  return __builtin_amdgcn_perm(ub, ua, 0x07060302u);
#endif
}
// tanh-GELU in sigmoid form, exp2-folded constants (log2e pre-multiplied):
// gelu(x) = x * rcp(1 + 2^(x * (c0 + c1*x^2))); ~7 VALU; |err| ~4e-4 abs.
__device__ __forceinline__ float gelu_fast(float x) {
  float t = fmaf(x * x, -0.10294443f, -2.3022091f);
  float e = __builtin_amdgcn_exp2f(x * t);
  return x * __builtin_amdgcn_rcpf(1.0f + e);
}

// ------------------------------- prep kernels ------------------------------
struct PrepParams {
  const float *Wc, *g1, *W1, *W2, *Wp, *g2, *W3, *W4, *h0, *h1, *h2;
  unsigned short* ws;
};

__global__ void prep_kernel(PrepParams pp) {
  const int K_[7]   = {192, 256, 256, 256, 260, 256, 128};
  const int Kp_[7]  = {192, 256, 256, 256, 272, 256, 128};
  const int OFF_[7] = {OFF_L1, OFF_W2, OFF_L3, OFF_W4, OFF_H0, OFF_H1, OFF_H2};
  for (int e = blockIdx.x * blockDim.x + threadIdx.x; e < SWZ_TOTAL;
       e += gridDim.x * blockDim.x) {
    int L = 0;
#pragma unroll
    for (int i = 1; i < 7; ++i) if (e >= OFF_[i]) L = i;
    int q = e - OFF_[L];
    int j = q & 7;
    int l = (q >> 3) & 63;
    int r = q >> 9;
    int nks = Kp_[L] >> 4;
    int ks = r % nks;
    int mt = r / nks;
    int n = mt * 32 + (l & 31);
    int k = ks * 16 + ((l >> 5) << 3) + j;
    float v = 0.0f;
    if (k < K_[L]) {
      if (L == 0) {
        if (k < 64) {  // (Wc @ diag(sig g1) @ W1)[k][n]
          float s = 0.0f;
          for (int q2 = 0; q2 < 128; ++q2) {
            float sg = 1.0f / (1.0f + expf(-pp.g1[q2]));
            s += pp.Wc[k * 128 + q2] * sg * pp.W1[q2 * 256 + n];
          }
          v = s;
        } else v = pp.W1[(k - 64) * 256 + n];
      } else if (L == 1) {
        v = pp.W2[k * 128 + n];
      } else if (L == 2) {
        if (k < 128) {  // (Wp @ diag(sig g2) @ W3)[k][n]
          float s = 0.0f;
          for (int q2 = 0; q2 < 128; ++q2) {
            float sg = 1.0f / (1.0f + expf(-pp.g2[q2]));
            s += pp.Wp[k * 128 + q2] * sg * pp.W3[q2 * 256 + n];
          }
          v = s;
        } else v = pp.W3[(k - 128) * 256 + n];
      } else if (L == 3) {
        v = pp.W4[k * 128 + n];
      } else if (L == 4) {
        v = pp.h0[k * 256 + n];
      } else if (L == 5) {
        v = pp.h1[k * 128 + n];
      } else {
        v = pp.h2[k * 64 + n];
      }
    }
    pp.ws[e] = f2bf(v);
  }
}

// fused biases: outB[0:256)=b1+bc@W1g, [256:512)=b3+bp@W3g  (fp32 in ws)
__global__ void prep_bias_kernel(const float* b1, const float* bc, const float* g1,
                                 const float* W1, const float* b3, const float* bp,
                                 const float* g2, const float* W3, float* outB) {
  int n = blockIdx.x * blockDim.x + threadIdx.x;
  if (n < 256) {
    float s = b1[n];
    for (int q = 0; q < 128; ++q) {
      float sg = 1.0f / (1.0f + expf(-g1[q]));
      s += bc[q] * sg * W1[q * 256 + n];
    }
    outB[n] = s;
  } else if (n < 512) {
    int m = n - 256;
    float s = b3[m];
    for (int q = 0; q < 128; ++q) {
      float sg = 1.0f / (1.0f + expf(-g2[q]));
      s += bp[q] * sg * W3[q * 256 + m];
    }
    outB[n] = s;
  }
}

// feat1 [B][C][H][W] fp32 -> ws [B][HW][C] bf16
__global__ void prep2_kernel(const float* __restrict__ f1, unsigned short* wsT) {
  for (int e = blockIdx.x * blockDim.x + threadIdx.x; e < NT_ELEMS;
       e += gridDim.x * blockDim.x) {
    int hw = e % HWs8;
    int c = (e / HWs8) & 127;
    int b = e / (HWs8 * 128);
    wsT[(b * HWs8 + hw) * 128 + c] = f2bf(f1[e]);
  }
}

// ------------------------------ main kernel --------------------------------
struct Params {
  const float* feat_s8; const float* feat_s16;
  const float* ctx_s8;  const float* coarse;
  const float* b2; const float* b4;
  const float* h0b; const float* h1b; const float* h2b;
  const float* h3w; const float* h3b;
  const unsigned short* ws;
  const unsigned short* wsT;
  const float* fbias;       // fused biases (fp32 in ws)
  float* out;
};

__device__ __forceinline__ void bilin_setup(float g, int Sg, int& i0, int& i1, float& w) {
  float s = (g + 1.0f) * (0.5f * Sg) - 0.5f;
  float f = floorf(s);
  w = s - f;
  int a = (int)f;
  i0 = min(max(a, 0), Sg - 1);
  i1 = min(max(a + 1, 0), Sg - 1);
}

// Patch index remap into buf's dead columns (float view):
// MAP 0: dword cols [96:128)  (ushort [192:256))  cap 2048 floats
// MAP 1: dword cols [128:144) (ushort [256:288))  cap 1024 floats
template<int MAP>
__device__ __forceinline__ int pmap(int n) {
  if (MAP == 0) return ((n >> 5) * SD) + 96 + (n & 31);
  else          return ((n >> 4) * SD) + 128 + (n & 15);
}

// 32x32x16 MFMA layer, K compile-time (full unroll).
// EP: 0=plain, 1=gelu, 2=relu. SYNC: barrier between B-reads and stores.
template<int MT, int NT, int EP, bool SYNC, int K>
__device__ __forceinline__ void mfma_layer(
    const unsigned short* __restrict__ Wsw,
    const float* __restrict__ bias,
    const unsigned short* actIn,
    unsigned short* actOut)
{
  const int t = threadIdx.x;
  const int l = t & 63;
  const int wv = t >> 6;
  constexpr int nks = K >> 4;
  const int mt0 = (NT == 2) ? wv * MT : (wv >> 1);
  const int ntb = (NT == 2) ? 0 : (wv & 1);
  const int lh = l >> 5;
  const int ll = l & 31;

  f32x16 acc[MT][NT];
#pragma unroll
  for (int m = 0; m < MT; ++m) {
#pragma unroll
    for (int g = 0; g < 4; ++g) {
      const int f0 = (mt0 + m) * 32 + g * 8 + (lh << 2);
      const float4 bv = *(const float4*)(bias + f0);
#pragma unroll
      for (int nt = 0; nt < NT; ++nt) {
        acc[m][nt][g * 4 + 0] = bv.x; acc[m][nt][g * 4 + 1] = bv.y;
        acc[m][nt][g * 4 + 2] = bv.z; acc[m][nt][g * 4 + 3] = bv.w;
      }
    }
  }

  const unsigned short* bbase = actIn + (ntb * 32 + ll) * S + (lh << 3);
  const unsigned short* abase = Wsw + (size_t)mt0 * nks * 512 + l * 8;

#pragma unroll
  for (int ks = 0; ks < nks; ++ks) {
    bf16x8 B[NT];
#pragma unroll
    for (int nt = 0; nt < NT; ++nt)
      B[nt] = *(const bf16x8*)(bbase + nt * 32 * S + ks * 16);
#pragma unroll
    for (int m = 0; m < MT; ++m) {
      bf16x8 A = *(const bf16x8*)(abase + ((size_t)m * nks + ks) * 512);
#pragma unroll
      for (int nt = 0; nt < NT; ++nt)
        acc[m][nt] = __builtin_amdgcn_mfma_f32_32x32x16_bf16(A, B[nt], acc[m][nt], 0, 0, 0);
    }
  }

  if (SYNC) ldsbar();

#pragma unroll
  for (int m = 0; m < MT; ++m) {
#pragma unroll
    for (int g = 0; g < 4; ++g) {
      const int f0 = (mt0 + m) * 32 + g * 8 + (lh << 2);
#pragma unroll
      for (int nt = 0; nt < NT; ++nt) {
        const int pt = (ntb + nt) * 32 + ll;
        float v[4];
        v[0] = acc[m][nt][g * 4 + 0]; v[1] = acc[m][nt][g * 4 + 1];
        v[2] = acc[m][nt][g * 4 + 2]; v[3] = acc[m][nt][g * 4 + 3];
        if (EP == 1) {
#pragma unroll
          for (int r = 0; r < 4; ++r) v[r] = gelu_fast(v[r]);
        } else if (EP == 2) {
#pragma unroll
          for (int r = 0; r < 4; ++r) v[r] = fmaxf(v[r], 0.0f);
        }
        uint2 pk;
        pk.x = pack2bf(v[0], v[1]);
        pk.y = pack2bf(v[2], v[3]);
        *(uint2*)(actOut + pt * S + f0) = pk;
      }
    }
  }
}

// stage a y-lerped patch into a remapped region of buf
template<int NCOL, int NCH, int MAP>
__device__ void stage_patch(const float* __restrict__ fm, int HW, int Wimg,
                            int base, int y0, int y1, float wy, float* bufF)
{
  const int items = NCOL * NCH;
  for (int e = threadIdx.x; e < items; e += NTH) {
    int ch = e / NCOL, col = e - ch * NCOL;
    int ca = min(base + col, Wimg - 1);
    const float* pp = fm + ch * HW;
    float v0 = pp[y0 * Wimg + ca];
    float v1 = pp[y1 * Wimg + ca];
    bufF[pmap<MAP>(col * (NCH + 2) + ch)] = fmaf(wy, v1 - v0, v0);
  }
}

// x-lerp from remapped patch into bf16 B-layout columns of buf
template<int PAIRS, int MAP, int CST>
__device__ void xlerp_tile(const float* __restrict__ bufF, const int* pcB, int shift,
                           const float* wxA, unsigned short* outBuf, int colOff)
{
  const int items = MP * PAIRS;
  for (int it = threadIdx.x; it < items; it += NTH) {
    int pr = it & (PAIRS - 1);
    int pt = it / PAIRS;
    int pc = pcB[pt] >> shift;
    int c0 = pc & 15, c1 = (pc >> 4) & 15;
    float wx = wxA[pt];
    float2 a = *(const float2*)(bufF + pmap<MAP>(c0 * CST + pr * 2));
    float2 b = *(const float2*)(bufF + pmap<MAP>(c1 * CST + pr * 2));
    float r0 = fmaf(wx, b.x - a.x, a.x);
    float r1 = fmaf(wx, b.y - a.y, a.y);
    *(unsigned*)(outBuf + pt * S + colOff + pr * 2) = pack2bf(r0, r1);
  }
}

// coalesced warped gather from transposed bf16 feat1 ([HW][C]); 4 ch/iter
__device__ void gather_tile_T(const unsigned short* __restrict__ T,
    const int* offT0, const int* offT1, const float* wxA, const float* wyA,
    unsigned short* outBuf, int colOff)
{
  for (int it = threadIdx.x; it < MP * 32; it += NTH) {
    int pt = it >> 5;
    int c4 = (it & 31) * 4;
    int e0 = offT0[pt], e1 = offT1[pt];
    int du = (e0 & 1) << 7;            // 0 or 128 (channel stride per +1 x)
    int o00 = e0 & ~1, o10 = e1 & ~1;
    float wx = wxA[pt], wy = wyA[pt];
    uint2 a00 = *(const uint2*)(T + o00 + c4);
    uint2 a01 = *(const uint2*)(T + o00 + du + c4);
    uint2 a10 = *(const uint2*)(T + o10 + c4);
    uint2 a11 = *(const uint2*)(T + o10 + du + c4);
    float w11 = wx * wy;
    float w01 = wx - w11, w10 = wy - w11, w00 = 1.0f - wx - wy + w11;
    float r0 = w00 * bflo(a00.x) + w01 * bflo(a01.x) + w10 * bflo(a10.x) + w11 * bflo(a11.x);
    float r1 = w00 * bfhi(a00.x) + w01 * bfhi(a01.x) + w10 * bfhi(a10.x) + w11 * bfhi(a11.x);
    float r2 = w00 * bflo(a00.y) + w01 * bflo(a01.y) + w10 * bflo(a10.y) + w11 * bflo(a11.y);
    float r3 = w00 * bfhi(a00.y) + w01 * bfhi(a01.y) + w10 * bfhi(a10.y) + w11 * bfhi(a11.y);
    uint2 pk;
    pk.x = pack2bf(r0, r1);
    pk.y = pack2bf(r2, r3);
    *(uint2*)(outBuf + pt * S + colOff + c4) = pk;
  }
}

__global__ __launch_bounds__(256, 4)
void ifd_kernel(Params p)
{
  __shared__ __align__(16) unsigned short buf[MP * S];   // 37888 B
  __shared__ int offT0[MP], offT1[MP];
  __shared__ int pcBoth[MP];
  __shared__ float w8x[MP], w16x[MP], wWx[MP], wWy[MP];
  __shared__ float caxA[MP], cayA[MP];

  float* bufF = (float*)buf;

  const int blk = blockIdx.x;
  const int bb = blk / (HF * BPR);
  const int r = blk % (HF * BPR);
  const int y = r >> 3;
  const int xb = (r & (BPR - 1)) * MP;
  const int t = threadIdx.x;
  const float lim = 1.0f - 1e-6f;

  // row-uniform bilinear params — computable by ALL threads, no barrier needed
  float gyu = fminf(fmaxf((y + 0.5f) * (2.0f / HF) - 1.0f, -lim), lim);
  int y80, y81; float wy8;
  bilin_setup(gyu, H8, y80, y81, wy8);
  int y160, y161; float wy16;
  bilin_setup(gyu, H16g, y160, y161, wy16);
  float gx0u = fminf(fmaxf((xb + 0.5f) * (2.0f / WF) - 1.0f, -lim), lim);
  int base8 = min(max((int)floorf((gx0u + 1.0f) * 32.0f - 0.5f), 0), W8 - 1);
  int base16 = min(max((int)floorf((gx0u + 1.0f) * 16.0f - 0.5f), 0), W16g - 1);

  // EARLY: issue f8 + ctx patch loads before per-point setup (overlaps the
  // global-load latency; LDS patch regions are disjoint from setup arrays)
  stage_patch<10, 128, 0>(p.feat_s8 + bb * 128 * HWs8, HWs8, W8,
                          base8, y80, y81, wy8, bufF);
  stage_patch<10, 64, 1>(p.ctx_s8 + bb * 64 * HWs8, HWs8, W8,
                         base8, y80, y81, wy8, bufF);

  if (t < MP) {
    const int i = t;
    const int x = xb + i;
    float gx = (x + 0.5f) * (2.0f / WF) - 1.0f;
    float gy = gyu;
    gx = fminf(fmaxf(gx, -lim), lim);

    int x0, x1; float wx;
    bilin_setup(gx, W8, x0, x1, wx);
    w8x[i] = wx;
    float wy = wy8;
    int o00 = y80 * W8 + x0, o01 = y80 * W8 + x1;
    int o10 = y81 * W8 + x0, o11 = y81 * W8 + x1;

    int a0, a1; float vx;
    bilin_setup(gx, W16g, a0, a1, vx);
    w16x[i] = vx;
    pcBoth[i] = (x0 - base8) | ((x1 - base8) << 4)
              | ((a0 - base16) << 8) | ((a1 - base16) << 12);

    const float* cf = p.coarse + bb * 2 * HWs8;
    float c00 = cf[o00], c01 = cf[o01], c10 = cf[o10], c11 = cf[o11];
    float cx0 = fmaf(wx, c01 - c00, c00), cx1 = fmaf(wx, c11 - c10, c10);
    float cfx = fmaf(wy, cx1 - cx0, cx0);
    const float* cf2 = cf + HWs8;
    c00 = cf2[o00]; c01 = cf2[o01]; c10 = cf2[o10]; c11 = cf2[o11];
    cx0 = fmaf(wx, c01 - c00, c00); cx1 = fmaf(wx, c11 - c10, c10);
    float cfy = fmaf(wy, cx1 - cx0, cx0);
    float cax = cfx * 8.0f, cay = cfy * 8.0f;
    caxA[i] = cax; cayA[i] = cay;

    float wxn = gx + cax * (2.0f / WF);
    float wyn = gy + cay * (2.0f / HF);
    wxn = fminf(fmaxf(wxn, -lim), lim);
    wyn = fminf(fmaxf(wyn, -lim), lim);
    int u0, u1, v0, v1; float uw, vw;
    bilin_setup(wxn, W8, u0, u1, uw);
    bilin_setup(wyn, H8, v0, v1, vw);
    int du = u1 - u0;   // 0 or 1
    offT0[i] = ((v0 * W8 + u0) << 7) | du;
    offT1[i] = ((v1 * W8 + u0) << 7) | du;
    wWx[i] = uw; wWy[i] = vw;
  }
  ldsbar();   // covers patch stores + setup arrays

  xlerp_tile<64, 0, 130>(bufF, pcBoth, 0, w8x, buf, 64);   // f8  -> [64:192)
  xlerp_tile<32, 1, 66>(bufF, pcBoth, 0, w8x, buf, 0);     // ctx -> [0:64)
  ldsbar();

  // stage f16 -> MAP1 (disjoint from L1 reads/writes); L1: [0:192) -> [0:256)
  stage_patch<6, 128, 1>(p.feat_s16 + bb * 128 * HWs16, HWs16, W16g,
                         base16, y160, y161, wy16, bufF);
  mfma_layer<2, 2, 1, true, 192>(p.ws + OFF_L1, p.fbias, buf, buf);
  ldsbar();
  // W2: [0:256) K=256 -> [0:128); then f16 x-lerp -> [128:256)
  mfma_layer<1, 2, 0, true, 256>(p.ws + OFF_W2, p.b2, buf, buf);
  xlerp_tile<64, 1, 130>(bufF, pcBoth, 8, w16x, buf, 128);
  ldsbar();
  // L3 (WpW3g | W3): [0:256) -> [0:256) gelu
  mfma_layer<2, 2, 1, true, 256>(p.ws + OFF_L3, p.fbias + 256, buf, buf);
  ldsbar();
  // W4: [0:256) -> [0:128); gather -> [128:256); extras -> [256:272)
  mfma_layer<1, 2, 0, true, 256>(p.ws + OFF_W4, p.b4, buf, buf);
  gather_tile_T(p.wsT + bb * HWs8 * 128, offT0, offT1, wWx, wWy, buf, 128);
  for (int idx = t; idx < MP * 8; idx += NTH) {
    int row = idx >> 3, c = idx & 7;
    unsigned val = 0;
    if (c == 0) {
      float gx = fminf(fmaxf((xb + row + 0.5f) * (2.0f / WF) - 1.0f, -lim), lim);
      val = pack2bf(gx, gyu);
    } else if (c == 1) {
      val = pack2bf(caxA[row] * (1.0f / WF), cayA[row] * (1.0f / HF));
    }
    *(unsigned*)(buf + row * S + 256 + c * 2) = val;
  }
  ldsbar();
  // flow head: H0 (K=272) and H1 in-place; H2 ping-pong [0:128)->[128:192)
  mfma_layer<2, 2, 2, true, 272>(p.ws + OFF_H0, p.h0b, buf, buf);
  ldsbar();
  mfma_layer<1, 2, 2, true, 256>(p.ws + OFF_H1, p.h1b, buf, buf);
  ldsbar();
  mfma_layer<1, 1, 2, false, 128>(p.ws + OFF_H2, p.h2b, buf, buf + 128);
  ldsbar();

  // final 64->2 + output (fp32); h3w from global (L2-hot)
  if (t < 128) {
    int i = t & 63, comp = t >> 6;
    float acc = p.h3b[comp];
    const unsigned short* rowp = buf + i * S + 128;
    const float* wp = p.h3w + comp;
#pragma unroll
    for (int k8 = 0; k8 < 8; ++k8) {
      uint4 av = *(const uint4*)(rowp + k8 * 8);
      const float* w8p = wp + k8 * 16;
      acc = fmaf(bflo(av.x), w8p[0], acc);
      acc = fmaf(bfhi(av.x), w8p[2], acc);
      acc = fmaf(bflo(av.y), w8p[4], acc);
      acc = fmaf(bfhi(av.y), w8p[6], acc);
      acc = fmaf(bflo(av.z), w8p[8], acc);
      acc = fmaf(bfhi(av.z), w8p[10], acc);
      acc = fmaf(bflo(av.w), w8p[12], acc);
      acc = fmaf(bfhi(av.w), w8p[14], acc);
    }
    float flow = (comp ? cayA[i] : caxA[i]) + acc * (comp ? (float)HF : (float)WF);
    p.out[((bb * 2 + comp) * HF + y) * WF + xb + i] = flow;
  }
}

extern "C" void kernel_launch(void* const* d_in, const int* in_sizes, int n_in,
                              void* d_out, int out_size, void* d_ws, size_t ws_size,
                              hipStream_t stream) {
  unsigned short* ws = (unsigned short*)d_ws;

  PrepParams pp;
  pp.Wc = (const float*)d_in[6];
  pp.g1 = (const float*)d_in[8];
  pp.W1 = (const float*)d_in[9];
  pp.W2 = (const float*)d_in[11];
  pp.Wp = (const float*)d_in[13];
  pp.g2 = (const float*)d_in[15];
  pp.W3 = (const float*)d_in[16];
  pp.W4 = (const float*)d_in[18];
  pp.h0 = (const float*)d_in[20];
  pp.h1 = (const float*)d_in[22];
  pp.h2 = (const float*)d_in[24];
  pp.ws = ws;
  hipLaunchKernelGGL(prep_kernel, dim3((SWZ_TOTAL + NTH - 1) / NTH), dim3(NTH), 0, stream, pp);
  hipLaunchKernelGGL(prep_bias_kernel, dim3(2), dim3(256), 0, stream,
                     (const float*)d_in[10], (const float*)d_in[7], (const float*)d_in[8],
                     (const float*)d_in[9],  (const float*)d_in[17], (const float*)d_in[14],
                     (const float*)d_in[15], (const float*)d_in[16], (float*)(ws + OFF_BF));
  hipLaunchKernelGGL(prep2_kernel, dim3(NT_ELEMS / NTH), dim3(NTH), 0, stream,
                     (const float*)d_in[2], ws + OFF_T);

  Params p;
  p.feat_s8  = (const float*)d_in[1];
  p.feat_s16 = (const float*)d_in[3];
  p.ctx_s8   = (const float*)d_in[4];
  p.coarse   = (const float*)d_in[5];
  p.b2  = (const float*)d_in[12];
  p.b4  = (const float*)d_in[19];
  p.h0b = (const float*)d_in[21];
  p.h1b = (const float*)d_in[23];
  p.h2b = (const float*)d_in[25];
  p.h3w = (const float*)d_in[26];
  p.h3b = (const float*)d_in[27];
  p.ws  = ws;
  p.wsT = ws + OFF_T;
  p.fbias = (const float*)(ws + OFF_BF);
  p.out = (float*)d_out;

  hipLaunchKernelGGL(ifd_kernel, dim3(NBLK), dim3(NTH), 0, stream, p);
}